// Round 16
// baseline (183.968 us; speedup 1.0000x reference)
//
#include <hip/hip_runtime.h>
#include <hip/hip_bf16.h>
#include <stdint.h>

#define BATCH 8192
#define PEP 15
#define INC 512
#define OUTC 512
#define XROW (PEP*INC)          // 7680 floats per batch row
#define WT_P_ELEMS (INC*OUTC)   // 262144 bf16 per p
#define NSTEPS 16               // K = 512 = 16 x 32

typedef float f32x4 __attribute__((ext_vector_type(4)));
typedef short s16x8 __attribute__((ext_vector_type(8)));
typedef unsigned int u32x4 __attribute__((ext_vector_type(4)));

__device__ __forceinline__ ushort f2b(float v) {
  // round-to-nearest-even fp32 -> bf16 (prep kernel)
  uint u = __float_as_uint(v);
  u += 0x7fffu + ((u >> 16) & 1u);
  return (ushort)(u >> 16);
}

__device__ __forceinline__ uint cvtpk(float a, float b) {
  // D[15:0]=bf16(a), D[31:16]=bf16(b); RNE. No builtin on gfx950 (T12 recipe).
  uint r;
  asm("v_cvt_pk_bf16_f32 %0, %1, %2" : "=v"(r) : "v"(a), "v"(b));
  return r;
}

// ---------------- kernel 1: W [p][k][n] fp32 -> fragment-linear bf16 (16x16x32) -------
// wt[(((p*16+ks)*32+n16)*64+l)*8+e] = bf16(W[p][ks*32+(l>>4)*8+e][n16*16+(l&15)])
// Per (ks,n16) the 64 lanes' 16B fragments are contiguous (1KB). Verified R1-R14.
__global__ __launch_bounds__(256) void wt_kernel(const float* __restrict__ w,
                                                 ushort* __restrict__ wt) {
  int gid = blockIdx.x * 256 + threadIdx.x;   // 15*16*32*64 = 491520 exactly
  int l   = gid & 63;
  int n16 = (gid >> 6) & 31;
  int ks  = (gid >> 11) & 15;
  int p   = gid >> 15;
  int fr = l & 15, g = l >> 4;
  const float* src = w + (size_t)p * WT_P_ELEMS + (size_t)(ks * 32 + g * 8) * OUTC + n16 * 16 + fr;
  s16x8 hv;
#pragma unroll
  for (int e = 0; e < 8; ++e) hv[e] = (short)f2b(src[(size_t)e * OUTC]);
  *(s16x8*)(wt + (size_t)gid * 8) = hv;
}

// ---------------- kernel 2: lgkm-barrier GEMM, deep rings, zero vmcnt(0) --------------
// BM=128 x BN=256, 512 thr (8 waves, wave owns 64m x 64n).
// NO __syncthreads, NO global_load_lds -> no forced vmcnt(0) drains anywhere.
// B: global->reg ring depth-3 (2-iter flight; wt L2-resident).
// A: global->reg ring depth-4 (3-iter flight > HBM latency) -> cvt_pk -> linear
//    ds_write into Ash[2]; cross-wave sync = asm lgkmcnt(0) + raw s_barrier (~30cy).
__global__ __launch_bounds__(512, 2) void gemm_kernel(const float* __restrict__ x,
                                                      const ushort* __restrict__ wt,
                                                      const float* __restrict__ bias,
                                                      float* __restrict__ out) {
  __shared__ __align__(16) char lds_raw[34816];  // main: A 2x8KB | epilogue: 8x4352B
  typedef ushort AshT[8][64][8];                 // [m16][lane][e]
  AshT* Ash = (AshT*)lds_raw;                    // Ash[buf], buf in {0,1}

  const int t    = threadIdx.x;
  const int lane = t & 63;
  const int wid  = t >> 6;        // 0..7
  const int wm   = wid >> 2;      // m-half
  const int wn   = wid & 3;       // n-quarter
  const int fr   = lane & 15;
  const int g    = lane >> 4;

  // grid: 1920 = 8 xcd * 240; j&1 = n-half (adjacent -> x L2-share), mb-major, p slow.
  const int bid  = blockIdx.x;
  const int xcd  = bid & 7;
  const int j    = bid >> 3;
  const int n2   = j & 1;
  const int pair = xcd * 120 + (j >> 1);   // 0..959 = 64 mb x 15 p
  const int mb   = pair & 63;
  const int p    = pair >> 6;
  const int m0   = mb * 128;

  // A staging: wave wid stages rows m0+wid*16..+16; lane (fr,g): row +fr, col g*8.
  const float* asrc = x + (size_t)(m0 + wid * 16 + fr) * XROW + p * INC + g * 8;
  // B: fragment-linear; wave reads n16 = n2*16 + wn*4 + nf.
  const ushort* bsrc = wt + (size_t)p * WT_P_ELEMS
                     + (size_t)(n2 * 16 + wn * 4) * 512 + (size_t)lane * 8;

  f32x4 acc[4][4] = {};             // [m16][nf] -> AGPRs
  f32x4 pa[4][2];                   // A ring depth-4: 32 VGPR
  s16x8 pbr[3][4];                  // B ring depth-3: 48 VGPR

  auto cvt_store = [&](int slot, int buf) {
    u32x4 aw;
    aw[0] = cvtpk(pa[slot][0][0], pa[slot][0][1]); aw[1] = cvtpk(pa[slot][0][2], pa[slot][0][3]);
    aw[2] = cvtpk(pa[slot][1][0], pa[slot][1][1]); aw[3] = cvtpk(pa[slot][1][2], pa[slot][1][3]);
    *(u32x4*)&Ash[buf][wid][lane][0] = aw;
  };

  // ---- prologue: A(0..3) -> pa ring; B(0),B(1) -> pbr; cvt A(0) -> Ash[0]; barrier
#pragma unroll
  for (int s = 0; s < 4; ++s) {
    pa[s][0] = *(const f32x4*)(asrc + s * 32);
    pa[s][1] = *(const f32x4*)(asrc + s * 32 + 4);
  }
#pragma unroll
  for (int nf = 0; nf < 4; ++nf) {
    pbr[0][nf] = *(const s16x8*)(bsrc + (size_t)nf * 512);
    pbr[1][nf] = *(const s16x8*)(bsrc + (size_t)16384 + nf * 512);
  }
  cvt_store(0, 0);                   // counted vmcnt on pa[0] only
  asm volatile("s_waitcnt lgkmcnt(0)" ::: "memory");
  __builtin_amdgcn_s_barrier();

#pragma unroll
  for (int ks = 0; ks < NSTEPS; ++ks) {
    // (1) issue: A(ks+4) -> pa[ks&3] (slot freed: A(ks) cvt'd last iter);
    //            B(ks+2) -> pbr[(ks+2)%3] (slot freed: B(ks-1) consumed last iter)
    if (ks < NSTEPS - 4) {
      pa[ks & 3][0] = *(const f32x4*)(asrc + (ks + 4) * 32);
      pa[ks & 3][1] = *(const f32x4*)(asrc + (ks + 4) * 32 + 4);
    }
    if (ks < NSTEPS - 2) {
#pragma unroll
      for (int nf = 0; nf < 4; ++nf)
        pbr[(ks + 2) % 3][nf] = *(const s16x8*)(bsrc + (size_t)(ks + 2) * 16384 + (size_t)nf * 512);
    }
    __builtin_amdgcn_sched_barrier(0);   // pin load issue before compute

    // (2) cvt A(ks+1) -> Ash[(ks+1)&1]  (pa slot loaded 3 iters ago: counted vmcnt)
    if (ks + 1 < NSTEPS) cvt_store((ks + 1) & 3, (ks + 1) & 1);

    // (3) A fragments for this wave's m-half (lane-contiguous, conflict-free)
    s16x8 af[4];
#pragma unroll
    for (int i = 0; i < 4; ++i)
      af[i] = *(const s16x8*)&Ash[ks & 1][wm * 4 + i][lane][0];

    // (4) MFMA (counted lgkm for af, counted vmcnt for pbr[ks%3])
#pragma unroll
    for (int i = 0; i < 4; ++i)
#pragma unroll
      for (int nf = 0; nf < 4; ++nf)
        acc[i][nf] = __builtin_amdgcn_mfma_f32_16x16x32_bf16(af[i], pbr[ks % 3][nf], acc[i][nf], 0, 0, 0);

    // (5) lgkm-only drain + raw barrier: my ds_write visible, my ds_reads done
    asm volatile("s_waitcnt lgkmcnt(0)" ::: "memory");
    __builtin_amdgcn_s_barrier();
  }

  // ---- epilogue: wave-private LDS transpose (stride 68) -> full-line stores ----
  // C/D layout col=lane&15, row=(lane>>4)*4+r (m89-verified).
  const int n0 = n2 * 256 + wn * 64;
  float bv[4];
#pragma unroll
  for (int nf = 0; nf < 4; ++nf) bv[nf] = bias[p * OUTC + n0 + nf * 16 + fr];

  float* trans = (float*)(lds_raw + wid * 4352);   // 16 x 68 f32 per wave
  const int er = lane >> 4;          // 0..3
  const int ec = (lane & 15) * 4;    // 0..60

#pragma unroll
  for (int m16 = 0; m16 < 4; ++m16) {
    __builtin_amdgcn_sched_barrier(0);
#pragma unroll
    for (int nf = 0; nf < 4; ++nf)
#pragma unroll
      for (int r = 0; r < 4; ++r)
        trans[(g * 4 + r) * 68 + nf * 16 + fr] = acc[m16][nf][r] + bv[nf];
    __builtin_amdgcn_sched_barrier(0);
    asm volatile("s_waitcnt lgkmcnt(0)" ::: "memory");
    __builtin_amdgcn_sched_barrier(0);
    float* ob = out + (size_t)(m0 + wm * 64 + m16 * 16) * XROW + p * INC + n0;
#pragma unroll
    for (int pass = 0; pass < 4; ++pass) {
      const int row = pass * 4 + er;
      f32x4 v = *(const f32x4*)&trans[row * 68 + ec];
      *(f32x4*)(ob + (size_t)row * XROW + ec) = v;
    }
    __builtin_amdgcn_sched_barrier(0);
    asm volatile("s_waitcnt lgkmcnt(0)" ::: "memory");   // reads landed before overwrite
    __builtin_amdgcn_sched_barrier(0);
  }
}

// ---------------- fallback (only if ws too small): naive fp32 ----------------
__global__ void naive_kernel(const float* __restrict__ x, const float* __restrict__ w,
                             const float* __restrict__ bias, float* __restrict__ out) {
  size_t i = (size_t)blockIdx.x * 256 + threadIdx.x;
  if (i >= (size_t)BATCH * PEP * OUTC) return;
  int o  = (int)(i & (OUTC - 1));
  int pp = (int)((i >> 9) % PEP);
  size_t b = i / ((size_t)PEP * OUTC);
  const float* xr = x + b * XROW + pp * INC;
  const float* wc = w + (size_t)pp * INC * OUTC + o;
  float s = bias[pp * OUTC + o];
  for (int k = 0; k < INC; ++k) s += xr[k] * wc[(size_t)k * OUTC];
  out[i] = s;
}

extern "C" void kernel_launch(void* const* d_in, const int* in_sizes, int n_in,
                              void* d_out, int out_size, void* d_ws, size_t ws_size,
                              hipStream_t stream) {
  const float* x    = (const float*)d_in[0];
  const float* w    = (const float*)d_in[1];
  const float* bias = (const float*)d_in[2];
  float* out = (float*)d_out;

  const size_t wt_bytes = (size_t)PEP * INC * OUTC * sizeof(ushort);  // 7.9 MB
  if (ws_size >= wt_bytes) {
    wt_kernel<<<1920, 256, 0, stream>>>(w, (ushort*)d_ws);
    gemm_kernel<<<1920, 512, 0, stream>>>(x, (const ushort*)d_ws, bias, out);
  } else {
    size_t total = (size_t)BATCH * PEP * OUTC;
    naive_kernel<<<(int)((total + 255) / 256), 256, 0, stream>>>(x, w, bias, out);
  }
}

// Round 17
// 149.531 us; speedup vs baseline: 1.2303x; 1.2303x over previous
//
#include <hip/hip_runtime.h>
#include <hip/hip_bf16.h>
#include <stdint.h>

#define BATCH 8192
#define PEP 15
#define INC 512
#define OUTC 512
#define XROW (PEP*INC)          // 7680 floats per batch row
#define WT_P_ELEMS (INC*OUTC)   // 262144 bf16 per p
#define NSTEPS 16               // K = 512 = 16 x 32

typedef float f32x4 __attribute__((ext_vector_type(4)));
typedef short s16x8 __attribute__((ext_vector_type(8)));
typedef unsigned int u32x4 __attribute__((ext_vector_type(4)));

__device__ __forceinline__ ushort f2b(float v) {
  // round-to-nearest-even fp32 -> bf16 (prep kernel)
  uint u = __float_as_uint(v);
  u += 0x7fffu + ((u >> 16) & 1u);
  return (ushort)(u >> 16);
}

__device__ __forceinline__ uint cvtpk(float a, float b) {
  // D[15:0]=bf16(a), D[31:16]=bf16(b); RNE. No builtin on gfx950 (T12 recipe).
  uint r;
  asm("v_cvt_pk_bf16_f32 %0, %1, %2" : "=v"(r) : "v"(a), "v"(b));
  return r;
}

// ---------------- kernel 1: W [p][k][n] fp32 -> fragment-linear bf16 (16x16x32) -------
// wt[(((p*16+ks)*32+n16)*64+l)*8+e] = bf16(W[p][ks*32+(l>>4)*8+e][n16*16+(l&15)])
// Per (ks,n16) the 64 lanes' 16B fragments are contiguous (1KB). Verified R1-R15.
__global__ __launch_bounds__(256) void wt_kernel(const float* __restrict__ w,
                                                 ushort* __restrict__ wt) {
  int gid = blockIdx.x * 256 + threadIdx.x;   // 15*16*32*64 = 491520 exactly
  int l   = gid & 63;
  int n16 = (gid >> 6) & 31;
  int ks  = (gid >> 11) & 15;
  int p   = gid >> 15;
  int fr = l & 15, g = l >> 4;
  const float* src = w + (size_t)p * WT_P_ELEMS + (size_t)(ks * 32 + g * 8) * OUTC + n16 * 16 + fr;
  s16x8 hv;
#pragma unroll
  for (int e = 0; e < 8; ++e) hv[e] = (short)f2b(src[(size_t)e * OUTC]);
  *(s16x8*)(wt + (size_t)gid * 8) = hv;
}

// ---------------- kernel 2: R14 skeleton + NONTEMPORAL epilogue stores ----------------
// BM=128 x BN=256, 512 thr (8 waves; wave (wm,wn) owns 64m x 64n).
// A: reg->cvt_pk->linear ds_write. B: global_load_lds fragment-linear. Double-buffer,
// ONE __syncthreads per K-step (best-measured R14 structure, 163.9us).
// NEW: out stores are nontemporal (write-once stream; bypass L2 allocate/evict).
__global__ __launch_bounds__(512, 4) void gemm_kernel(const float* __restrict__ x,
                                                      const ushort* __restrict__ wt,
                                                      const float* __restrict__ bias,
                                                      float* __restrict__ out) {
  __shared__ __align__(16) char lds_raw[49152];   // 48KB: A 2x8KB | B 2x16KB
  typedef ushort AshT[8][64][8];
  typedef ushort BshT[16][64][8];
  AshT* Ash = (AshT*)lds_raw;                    // Ash[buf][m16][lane][e]
  BshT* Bsh = (BshT*)(lds_raw + 16384);          // Bsh[buf][n16][lane][e]

  const int t    = threadIdx.x;
  const int lane = t & 63;
  const int wid  = t >> 6;        // 0..7
  const int wm   = wid >> 2;      // 0..1 : m-half
  const int wn   = wid & 3;       // 0..3 : n-quarter
  const int fr   = lane & 15;
  const int g    = lane >> 4;

  // grid: 1920 = 8 xcd * 240; within XCD: j&1 = n-half (adjacent -> x L2-share),
  // then mb fastest (mb-major keeps wt slice L2-resident), p slowest.
  const int bid  = blockIdx.x;
  const int xcd  = bid & 7;
  const int j    = bid >> 3;               // 0..239
  const int n2   = j & 1;
  const int pair = xcd * 120 + (j >> 1);   // 0..959 = 64 mb x 15 p
  const int mb   = pair & 63;
  const int p    = pair >> 6;
  const int m0   = mb * 128;

  // ---- A addressing: wave wid stages rows m0+wid*16..+16; lane (fr,g) reads
  //      row m0+wid*16+fr, cols ks*32+g*8..+8. ds_write slot == lane (linear).
  const float* asrc = x + (size_t)(m0 + wid * 16 + fr) * XROW + p * INC + g * 8;

  // ---- B DMA source: fragment-linear wt; wave wid stages n16 = n2*16 + wid*2 + q
  const ushort* bsrc = wt + (size_t)p * WT_P_ELEMS
                     + (size_t)(n2 * 16 + wid * 2) * 512 + (size_t)lane * 8;

  f32x4 acc[4][4] = {};             // [m16][nf] for this wave's 64x64 tile
  f32x4 pa0, pa1;                   // A staging regs (8 floats)

  auto cvt_store = [&](int buf) {
    u32x4 aw;
    aw[0] = cvtpk(pa0[0], pa0[1]); aw[1] = cvtpk(pa0[2], pa0[3]);
    aw[2] = cvtpk(pa1[0], pa1[1]); aw[3] = cvtpk(pa1[2], pa1[3]);
    *(u32x4*)&Ash[buf][wid][lane][0] = aw;
  };
  auto stageB = [&](int ks, int buf) {
#pragma unroll
    for (int q = 0; q < 2; ++q) {
      __builtin_amdgcn_global_load_lds(
          (const __attribute__((address_space(1))) void*)(bsrc + (size_t)ks * 16384 + q * 512),
          (__attribute__((address_space(3))) void*)(&Bsh[buf][wid * 2 + q][lane][0]),
          16, 0, 0);
    }
  };

  // ---- prologue: A(0) -> LDS, B(0) DMA, A(1) -> regs
  pa0 = *(const f32x4*)(asrc);
  pa1 = *(const f32x4*)(asrc + 4);
  cvt_store(0);
  stageB(0, 0);
  pa0 = *(const f32x4*)(asrc + 32);
  pa1 = *(const f32x4*)(asrc + 36);
  __syncthreads();

#pragma unroll
  for (int ks = 0; ks < NSTEPS; ++ks) {
    const int cur = ks & 1;
    const int nxt = cur ^ 1;

    // stage(ks+1): A from regs (cvt once), B via DMA
    if (ks + 1 < NSTEPS) {
      cvt_store(nxt);
      stageB(ks + 1, nxt);
    }
    // refill A regs for ks+2
    if (ks + 2 < NSTEPS) {
      pa0 = *(const f32x4*)(asrc + (ks + 2) * 32);
      pa1 = *(const f32x4*)(asrc + (ks + 2) * 32 + 4);
    }

    // A fragments for this wave's m-half (linear lane-contiguous, conflict-free)
    s16x8 af[4];
#pragma unroll
    for (int i = 0; i < 4; ++i)
      af[i] = *(const s16x8*)&Ash[cur][wm * 4 + i][lane][0];

    // B fragments for this wave's n-quarter (lane-contiguous, conflict-free)
    s16x8 bf[4];
#pragma unroll
    for (int nf = 0; nf < 4; ++nf)
      bf[nf] = *(const s16x8*)&Bsh[cur][wn * 4 + nf][lane][0];

#pragma unroll
    for (int i = 0; i < 4; ++i)
#pragma unroll
      for (int nf = 0; nf < 4; ++nf)
        acc[i][nf] = __builtin_amdgcn_mfma_f32_16x16x32_bf16(af[i], bf[nf], acc[i][nf], 0, 0, 0);

    __syncthreads();   // single drain point per K-step (R14-verified best structure)
  }

  // ---- epilogue: wave-private LDS transpose (stride 68) -> NONTEMPORAL full-line stores
  // C/D layout col=lane&15, row=(lane>>4)*4+r (m89-verified).
  const int n0 = n2 * 256 + wn * 64;
  float bv[4];
#pragma unroll
  for (int nf = 0; nf < 4; ++nf) bv[nf] = bias[p * OUTC + n0 + nf * 16 + fr];

  float* trans = (float*)(lds_raw + wid * 4352);   // 16 x 68 f32 per wave
  const int er = lane >> 4;          // 0..3
  const int ec = (lane & 15) * 4;    // 0..60

#pragma unroll
  for (int m16 = 0; m16 < 4; ++m16) {
    __builtin_amdgcn_sched_barrier(0);
#pragma unroll
    for (int nf = 0; nf < 4; ++nf)
#pragma unroll
      for (int r = 0; r < 4; ++r)
        trans[(g * 4 + r) * 68 + nf * 16 + fr] = acc[m16][nf][r] + bv[nf];
    __builtin_amdgcn_sched_barrier(0);
    asm volatile("s_waitcnt lgkmcnt(0)" ::: "memory");
    __builtin_amdgcn_sched_barrier(0);
    float* ob = out + (size_t)(m0 + wm * 64 + m16 * 16) * XROW + p * INC + n0;
#pragma unroll
    for (int pass = 0; pass < 4; ++pass) {
      const int row = pass * 4 + er;
      f32x4 v = *(const f32x4*)&trans[row * 68 + ec];
      __builtin_nontemporal_store(v, (f32x4*)(ob + (size_t)row * XROW + ec));
    }
    __builtin_amdgcn_sched_barrier(0);
    asm volatile("s_waitcnt lgkmcnt(0)" ::: "memory");   // reads landed before overwrite
    __builtin_amdgcn_sched_barrier(0);
  }
}

// ---------------- fallback (only if ws too small): naive fp32 ----------------
__global__ void naive_kernel(const float* __restrict__ x, const float* __restrict__ w,
                             const float* __restrict__ bias, float* __restrict__ out) {
  size_t i = (size_t)blockIdx.x * 256 + threadIdx.x;
  if (i >= (size_t)BATCH * PEP * OUTC) return;
  int o  = (int)(i & (OUTC - 1));
  int pp = (int)((i >> 9) % PEP);
  size_t b = i / ((size_t)PEP * OUTC);
  const float* xr = x + b * XROW + pp * INC;
  const float* wc = w + (size_t)pp * INC * OUTC + o;
  float s = bias[pp * OUTC + o];
  for (int k = 0; k < INC; ++k) s += xr[k] * wc[(size_t)k * OUTC];
  out[i] = s;
}

extern "C" void kernel_launch(void* const* d_in, const int* in_sizes, int n_in,
                              void* d_out, int out_size, void* d_ws, size_t ws_size,
                              hipStream_t stream) {
  const float* x    = (const float*)d_in[0];
  const float* w    = (const float*)d_in[1];
  const float* bias = (const float*)d_in[2];
  float* out = (float*)d_out;

  const size_t wt_bytes = (size_t)PEP * INC * OUTC * sizeof(ushort);  // 7.9 MB
  if (ws_size >= wt_bytes) {
    wt_kernel<<<1920, 256, 0, stream>>>(w, (ushort*)d_ws);
    gemm_kernel<<<1920, 512, 0, stream>>>(x, (const ushort*)d_ws, bias, out);
  } else {
    size_t total = (size_t)BATCH * PEP * OUTC;
    naive_kernel<<<(int)((total + 255) / 256), 256, 0, stream>>>(x, w, bias, out);
  }
}

// Round 18
// 149.099 us; speedup vs baseline: 1.2339x; 1.0029x over previous
//
#include <hip/hip_runtime.h>
#include <hip/hip_bf16.h>
#include <stdint.h>

#define BATCH 8192
#define PEP 15
#define INC 512
#define OUTC 512
#define XROW (PEP*INC)          // 7680 floats per batch row
#define WT_P_ELEMS (INC*OUTC)   // 262144 bf16 per p
#define NSTEPS 16               // K = 512 = 16 x 32

typedef float f32x4 __attribute__((ext_vector_type(4)));
typedef short s16x8 __attribute__((ext_vector_type(8)));
typedef unsigned int u32x4 __attribute__((ext_vector_type(4)));

__device__ __forceinline__ ushort f2b(float v) {
  // round-to-nearest-even fp32 -> bf16 (prep kernel)
  uint u = __float_as_uint(v);
  u += 0x7fffu + ((u >> 16) & 1u);
  return (ushort)(u >> 16);
}

__device__ __forceinline__ uint cvtpk(float a, float b) {
  // D[15:0]=bf16(a), D[31:16]=bf16(b); RNE. No builtin on gfx950 (T12 recipe).
  uint r;
  asm("v_cvt_pk_bf16_f32 %0, %1, %2" : "=v"(r) : "v"(a), "v"(b));
  return r;
}

// ---------------- kernel 1: W [p][k][n] fp32 -> fragment-linear bf16 (16x16x32) -------
// wt[(((p*16+ks)*32+n16)*64+l)*8+e] = bf16(W[p][ks*32+(l>>4)*8+e][n16*16+(l&15)])
// Per (ks,n16) the 64 lanes' 16B fragments are contiguous (1KB). Verified R1-R16.
__global__ __launch_bounds__(256) void wt_kernel(const float* __restrict__ w,
                                                 ushort* __restrict__ wt) {
  int gid = blockIdx.x * 256 + threadIdx.x;   // 15*16*32*64 = 491520 exactly
  int l   = gid & 63;
  int n16 = (gid >> 6) & 31;
  int ks  = (gid >> 11) & 15;
  int p   = gid >> 15;
  int fr = l & 15, g = l >> 4;
  const float* src = w + (size_t)p * WT_P_ELEMS + (size_t)(ks * 32 + g * 8) * OUTC + n16 * 16 + fr;
  s16x8 hv;
#pragma unroll
  for (int e = 0; e < 8; ++e) hv[e] = (short)f2b(src[(size_t)e * OUTC]);
  *(s16x8*)(wt + (size_t)gid * 8) = hv;
}

// ---------------- kernel 2: R16 main loop + block-cooperative 1KB-burst NT epilogue ---
// BM=128 x BN=256, 512 thr (8 waves; wave (wm,wn) owns 64m x 64n).
// A: reg->cvt_pk->linear ds_write. B: global_load_lds fragment-linear. Double-buffer,
// ONE __syncthreads per K-step. Epilogue: all waves assemble 32 full output rows in
// LDS, then each wave streams one FULL 1KB contiguous row per NT store instruction.
__global__ __launch_bounds__(512, 4) void gemm_kernel(const float* __restrict__ x,
                                                      const ushort* __restrict__ wt,
                                                      const float* __restrict__ bias,
                                                      float* __restrict__ out) {
  __shared__ __align__(16) char lds_raw[49152];   // 48KB: A 2x8KB | B 2x16KB ; epilogue reuse
  typedef ushort AshT[8][64][8];
  typedef ushort BshT[16][64][8];
  AshT* Ash = (AshT*)lds_raw;                    // Ash[buf][m16][lane][e]
  BshT* Bsh = (BshT*)(lds_raw + 16384);          // Bsh[buf][n16][lane][e]

  const int t    = threadIdx.x;
  const int lane = t & 63;
  const int wid  = t >> 6;        // 0..7
  const int wm   = wid >> 2;      // 0..1 : m-half
  const int wn   = wid & 3;       // 0..3 : n-quarter
  const int fr   = lane & 15;
  const int g    = lane >> 4;

  // grid: 1920 = 8 xcd * 240; within XCD: j&1 = n-half (adjacent -> x L2-share),
  // then mb fastest (mb-major keeps wt slice L2-resident), p slowest.
  const int bid  = blockIdx.x;
  const int xcd  = bid & 7;
  const int j    = bid >> 3;               // 0..239
  const int n2   = j & 1;
  const int pair = xcd * 120 + (j >> 1);   // 0..959 = 64 mb x 15 p
  const int mb   = pair & 63;
  const int p    = pair >> 6;
  const int m0   = mb * 128;

  // ---- A addressing: wave wid stages rows m0+wid*16..+16; lane (fr,g) reads
  //      row m0+wid*16+fr, cols ks*32+g*8..+8. ds_write slot == lane (linear).
  const float* asrc = x + (size_t)(m0 + wid * 16 + fr) * XROW + p * INC + g * 8;

  // ---- B DMA source: fragment-linear wt; wave wid stages n16 = n2*16 + wid*2 + q
  const ushort* bsrc = wt + (size_t)p * WT_P_ELEMS
                     + (size_t)(n2 * 16 + wid * 2) * 512 + (size_t)lane * 8;

  f32x4 acc[4][4] = {};             // [m16][nf] for this wave's 64x64 tile
  f32x4 pa0, pa1;                   // A staging regs (8 floats)

  auto cvt_store = [&](int buf) {
    u32x4 aw;
    aw[0] = cvtpk(pa0[0], pa0[1]); aw[1] = cvtpk(pa0[2], pa0[3]);
    aw[2] = cvtpk(pa1[0], pa1[1]); aw[3] = cvtpk(pa1[2], pa1[3]);
    *(u32x4*)&Ash[buf][wid][lane][0] = aw;
  };
  auto stageB = [&](int ks, int buf) {
#pragma unroll
    for (int q = 0; q < 2; ++q) {
      __builtin_amdgcn_global_load_lds(
          (const __attribute__((address_space(1))) void*)(bsrc + (size_t)ks * 16384 + q * 512),
          (__attribute__((address_space(3))) void*)(&Bsh[buf][wid * 2 + q][lane][0]),
          16, 0, 0);
    }
  };

  // ---- prologue: A(0) -> LDS, B(0) DMA, A(1) -> regs
  pa0 = *(const f32x4*)(asrc);
  pa1 = *(const f32x4*)(asrc + 4);
  cvt_store(0);
  stageB(0, 0);
  pa0 = *(const f32x4*)(asrc + 32);
  pa1 = *(const f32x4*)(asrc + 36);
  __syncthreads();

#pragma unroll
  for (int ks = 0; ks < NSTEPS; ++ks) {
    const int cur = ks & 1;
    const int nxt = cur ^ 1;

    // stage(ks+1): A from regs (cvt once), B via DMA
    if (ks + 1 < NSTEPS) {
      cvt_store(nxt);
      stageB(ks + 1, nxt);
    }
    // refill A regs for ks+2
    if (ks + 2 < NSTEPS) {
      pa0 = *(const f32x4*)(asrc + (ks + 2) * 32);
      pa1 = *(const f32x4*)(asrc + (ks + 2) * 32 + 4);
    }

    // A fragments for this wave's m-half (linear lane-contiguous, conflict-free)
    s16x8 af[4];
#pragma unroll
    for (int i = 0; i < 4; ++i)
      af[i] = *(const s16x8*)&Ash[cur][wm * 4 + i][lane][0];

    // B fragments for this wave's n-quarter (lane-contiguous, conflict-free)
    s16x8 bf[4];
#pragma unroll
    for (int nf = 0; nf < 4; ++nf)
      bf[nf] = *(const s16x8*)&Bsh[cur][wn * 4 + nf][lane][0];

#pragma unroll
    for (int i = 0; i < 4; ++i)
#pragma unroll
      for (int nf = 0; nf < 4; ++nf)
        acc[i][nf] = __builtin_amdgcn_mfma_f32_16x16x32_bf16(af[i], bf[nf], acc[i][nf], 0, 0, 0);

    __syncthreads();   // single drain point per K-step (R14/R16-verified)
  }

  // ---- epilogue: block-cooperative row assembly -> 1KB-contiguous NT bursts ----
  // C/D layout col=lane&15, row=(lane>>4)*4+r (m89-verified).
  // Step s (0..3): wm-half waves deposit acc[s] (m16 = wm*4+s) into region[wm]
  // (16 rows x 260 f32, pad->2-way-free); then wave w streams row pass*8+w as ONE
  // 1KB contiguous NT store (64 lanes x 16B). Sync = lgkmcnt(0) + raw s_barrier.
  const int n0q = wn * 64;
  float bv[4];
#pragma unroll
  for (int nf = 0; nf < 4; ++nf) bv[nf] = bias[p * OUTC + n2 * 256 + n0q + nf * 16 + fr];

  float* reg0 = (float*)lds_raw;                 // region[0]: 16 x 260 f32
  float* reg1 = (float*)lds_raw + 16 * 260;      // region[1]
  float* myreg = wm ? reg1 : reg0;
  const float* obase = out + p * INC + n2 * 256 + lane * 4;

#pragma unroll
  for (int s = 0; s < 4; ++s) {
    __builtin_amdgcn_sched_barrier(0);
    // deposit this wave's acc[s] into its region (2-way bank alias = free)
#pragma unroll
    for (int nf = 0; nf < 4; ++nf)
#pragma unroll
      for (int r = 0; r < 4; ++r)
        myreg[(g * 4 + r) * 260 + n0q + nf * 16 + fr] = acc[s][nf][r] + bv[nf];
    __builtin_amdgcn_sched_barrier(0);
    asm volatile("s_waitcnt lgkmcnt(0)" ::: "memory");
    __builtin_amdgcn_s_barrier();
    __builtin_amdgcn_sched_barrier(0);

    // stream 32 rows; wave w writes row pass*8+w as one 1KB NT burst
#pragma unroll
    for (int pass = 0; pass < 4; ++pass) {
      const int row_id = pass * 8 + wid;        // 0..31
      const int rgn = row_id >> 4;              // m-half
      const int rw  = row_id & 15;
      f32x4 v = *(const f32x4*)((rgn ? reg1 : reg0) + rw * 260 + lane * 4);
      __builtin_nontemporal_store(v,
          (f32x4*)((float*)obase + (size_t)(m0 + rgn * 64 + s * 16 + rw) * XROW));
    }
    __builtin_amdgcn_sched_barrier(0);
    asm volatile("s_waitcnt lgkmcnt(0)" ::: "memory");   // LDS reads done before next deposit
    __builtin_amdgcn_s_barrier();
    __builtin_amdgcn_sched_barrier(0);
  }
}

// ---------------- fallback (only if ws too small): naive fp32 ----------------
__global__ void naive_kernel(const float* __restrict__ x, const float* __restrict__ w,
                             const float* __restrict__ bias, float* __restrict__ out) {
  size_t i = (size_t)blockIdx.x * 256 + threadIdx.x;
  if (i >= (size_t)BATCH * PEP * OUTC) return;
  int o  = (int)(i & (OUTC - 1));
  int pp = (int)((i >> 9) % PEP);
  size_t b = i / ((size_t)PEP * OUTC);
  const float* xr = x + b * XROW + pp * INC;
  const float* wc = w + (size_t)pp * INC * OUTC + o;
  float s = bias[pp * OUTC + o];
  for (int k = 0; k < INC; ++k) s += xr[k] * wc[(size_t)k * OUTC];
  out[i] = s;
}

extern "C" void kernel_launch(void* const* d_in, const int* in_sizes, int n_in,
                              void* d_out, int out_size, void* d_ws, size_t ws_size,
                              hipStream_t stream) {
  const float* x    = (const float*)d_in[0];
  const float* w    = (const float*)d_in[1];
  const float* bias = (const float*)d_in[2];
  float* out = (float*)d_out;

  const size_t wt_bytes = (size_t)PEP * INC * OUTC * sizeof(ushort);  // 7.9 MB
  if (ws_size >= wt_bytes) {
    wt_kernel<<<1920, 256, 0, stream>>>(w, (ushort*)d_ws);
    gemm_kernel<<<1920, 512, 0, stream>>>(x, (const ushort*)d_ws, bias, out);
  } else {
    size_t total = (size_t)BATCH * PEP * OUTC;
    naive_kernel<<<(int)((total + 255) / 256), 256, 0, stream>>>(x, w, bias, out);
  }
}